// Round 1
// baseline (465.327 us; speedup 1.0000x reference)
//
#include <hip/hip_runtime.h>

#define HID 32
#define SEQ 512
#define GROUPS_PER_BLOCK 8
#define BLOCK (GROUPS_PER_BLOCK * 32)

__device__ __forceinline__ float fast_exp(float x) {
    // e^x = 2^(x * log2(e)), v_exp_f32 ~1 ulp
    return __builtin_amdgcn_exp2f(x * 1.44269504088896340736f);
}
__device__ __forceinline__ float fast_rcp(float x) {
    return __builtin_amdgcn_rcpf(x);
}
__device__ __forceinline__ float sigmoid_f(float x) {
    return fast_rcp(1.0f + fast_exp(-x));
}
__device__ __forceinline__ float tanh_f(float x) {
    // tanh(x) = 1 - 2/(1 + e^{2x}); saturates correctly at +/-inf
    return 1.0f - 2.0f * fast_rcp(1.0f + fast_exp(2.0f * x));
}

__global__ __launch_bounds__(BLOCK, 2) void lstm_fused_kernel(
    const float* __restrict__ x,       // [B, T, 1]
    const float* __restrict__ W_ih,    // [4H, 1]
    const float* __restrict__ W_hh,    // [4H, H] row-major
    const float* __restrict__ b_ih,    // [4H]
    const float* __restrict__ b_hh,    // [4H]
    const float* __restrict__ W_head,  // [1, H]
    const float* __restrict__ b_head,  // [1]
    float* __restrict__ out)           // [B, 1]
{
    // Stage W_hh transposed into LDS: Wl[j][g] with padded stride 129
    // (write banks (j+g)%32 distinct across consecutive tids; read banks
    // (j+k)%32 distinct across the 32 lanes of a group -> conflict-free)
    __shared__ float Wl[32 * 129];
    const int tid = threadIdx.x;
    for (int idx = tid; idx < 128 * 32; idx += BLOCK) {
        const int g = idx >> 5;   // gate-row 0..127
        const int j = idx & 31;   // hidden col 0..31
        Wl[j * 129 + g] = W_hh[idx];
    }
    __syncthreads();

    const int k   = tid & 31;   // hidden unit owned by this lane
    const int grp = tid >> 5;   // batch group within block (0..7)
    const int b   = blockIdx.x * GROUPS_PER_BLOCK + grp;

    // Pull this lane's 4 weight rows (gates i,f,g,o for unit k) into VGPRs.
    float wi[HID], wf[HID], wg[HID], wo[HID];
#pragma unroll
    for (int j = 0; j < HID; ++j) {
        wi[j] = Wl[j * 129 +       k];
        wf[j] = Wl[j * 129 +  32 + k];
        wg[j] = Wl[j * 129 +  64 + k];
        wo[j] = Wl[j * 129 +  96 + k];
    }

    const float bi = b_ih[k]      + b_hh[k];
    const float bf = b_ih[32 + k] + b_hh[32 + k];
    const float bg = b_ih[64 + k] + b_hh[64 + k];
    const float bo = b_ih[96 + k] + b_hh[96 + k];
    const float ui = W_ih[k];
    const float uf = W_ih[32 + k];
    const float ug = W_ih[64 + k];
    const float uo = W_ih[96 + k];

    const float* xb = x + (size_t)b * SEQ;  // I == 1, so x[b][t][0] = xb[t]

    float h = 0.0f, c = 0.0f;

    for (int t0 = 0; t0 < SEQ; t0 += 32) {
        // lane k prefetches x[b][t0+k]; broadcast per-step via shuffle
        const float xv = xb[t0 + k];
#pragma unroll 4
        for (int tt = 0; tt < 32; ++tt) {
            const float xt = __shfl(xv, tt, 32);
            float pi = __builtin_fmaf(xt, ui, bi);
            float pf = __builtin_fmaf(xt, uf, bf);
            float pg = __builtin_fmaf(xt, ug, bg);
            float po = __builtin_fmaf(xt, uo, bo);
#pragma unroll
            for (int j = 0; j < HID; ++j) {
                const float hj = __shfl(h, j, 32);
                pi = __builtin_fmaf(hj, wi[j], pi);
                pf = __builtin_fmaf(hj, wf[j], pf);
                pg = __builtin_fmaf(hj, wg[j], pg);
                po = __builtin_fmaf(hj, wo[j], po);
            }
            const float ig = sigmoid_f(pi);
            const float fg = sigmoid_f(pf);
            const float gg = tanh_f(pg);
            const float og = sigmoid_f(po);
            c = __builtin_fmaf(fg, c, ig * gg);
            h = og * tanh_f(c);
        }
    }

    // head: out[b] = sum_k h[k] * W_head[0][k] + b_head[0]
    float v = h * W_head[k];
#pragma unroll
    for (int off = 16; off >= 1; off >>= 1)
        v += __shfl_xor(v, off, 32);
    if (k == 0) out[b] = v + b_head[0];
}

extern "C" void kernel_launch(void* const* d_in, const int* in_sizes, int n_in,
                              void* d_out, int out_size, void* d_ws, size_t ws_size,
                              hipStream_t stream) {
    const float* x      = (const float*)d_in[0];
    const float* W_ih   = (const float*)d_in[1];
    const float* W_hh   = (const float*)d_in[2];
    const float* b_ih   = (const float*)d_in[3];
    const float* b_hh   = (const float*)d_in[4];
    const float* W_head = (const float*)d_in[5];
    const float* b_head = (const float*)d_in[6];
    float* out = (float*)d_out;

    const int B = in_sizes[0] / SEQ;          // 4096
    const int grid = B / GROUPS_PER_BLOCK;    // 512 blocks

    lstm_fused_kernel<<<grid, BLOCK, 0, stream>>>(
        x, W_ih, W_hh, b_ih, b_hh, W_head, b_head, out);
}